// Round 2
// baseline (753.099 us; speedup 1.0000x reference)
//
#include <hip/hip_runtime.h>

// out[b,m,n] = sum_k W[m,k]*X[b,k,n] + bias[m],  W=[W_e|W_h] (128x256),
// X=[e_vw;h_w] (256x512 per batch). Memory-bound batched GEMM.
//
// Design (round 2): no X transpose, no inner barriers.
//  - Lane (quad,l15) loads X[k=s*32+quad*8+j][ncol] straight into the MFMA
//    B-fragment layout (B[k=quad*8+j][n=l15]) -> 8 resident bf16x8 frags.
//  - W converted to bf16 and staged in LDS ONCE per block (64 KB), atom-XOR
//    swizzled so A-fragment ds_read_b128 is 2 lanes/bank (free).
//  - Wave owns 16 cols x 128 rows; m-tiles looped, acc = 4 VGPRs at a time.
//  - 512 thr/block (8 waves), grid 1024x4; 2 blocks/CU, 16 waves/CU.

typedef __bf16 bf16x8 __attribute__((ext_vector_type(8)));
typedef float  f32x4  __attribute__((ext_vector_type(4)));

#define NDIM 512

__global__ __launch_bounds__(512, 4) void msg_kernel(
    const float* __restrict__ h_w,
    const float* __restrict__ e_vw,
    const float* __restrict__ W_e,
    const float* __restrict__ b_e,
    const float* __restrict__ W_h,
    const float* __restrict__ b_h,
    float* __restrict__ out)
{
  // Ws[m][slot]: row m = 256 bf16 (32 atoms of 8); atom a stored at slot a^(m&7)
  __shared__ __align__(16) __bf16 Ws[128 * 256];   // 64 KB exactly

  const int tid  = threadIdx.x;
  const int lane = tid & 63;
  const int wave = tid >> 6;          // 0..7
  const int l15  = lane & 15;
  const int quad = lane >> 4;

  const int b    = blockIdx.x >> 2;
  const int nq   = blockIdx.x & 3;
  const int ncol = nq * 128 + wave * 16 + l15;   // this lane's output column

  // ---- X loads: 64 dwords/lane, k = s*32 + quad*8 + j (s<4: e_vw, s>=4: h_w)
  const float* pe = e_vw + ((size_t)b * 128 + quad * 8) * NDIM + ncol;
  const float* ph = h_w  + ((size_t)b * 128 + quad * 8) * NDIM + ncol;
  float xs[8][8];
#pragma unroll
  for (int s = 0; s < 4; ++s)
#pragma unroll
    for (int j = 0; j < 8; ++j)
      xs[s][j] = pe[(size_t)(s * 32 + j) * NDIM];
#pragma unroll
  for (int s = 0; s < 4; ++s)
#pragma unroll
    for (int j = 0; j < 8; ++j)
      xs[4 + s][j] = ph[(size_t)(s * 32 + j) * NDIM];

  // ---- W staging: 4096 16B-atoms; thread does 8 (4 from W_e, 4 from W_h).
  // Atom A = 8 consecutive floats of row m=A>>4 (rows are 128 floats = 16 atoms).
#pragma unroll
  for (int i = 0; i < 4; ++i) {
    const int A = i * 512 + tid;            // 0..2047 -> W_e
    const int m = A >> 4, a = A & 15;
    f32x4 lo = *(const f32x4*)(W_e + A * 8);
    f32x4 hi = *(const f32x4*)(W_e + A * 8 + 4);
    bf16x8 v;
    v[0]=(__bf16)lo[0]; v[1]=(__bf16)lo[1]; v[2]=(__bf16)lo[2]; v[3]=(__bf16)lo[3];
    v[4]=(__bf16)hi[0]; v[5]=(__bf16)hi[1]; v[6]=(__bf16)hi[2]; v[7]=(__bf16)hi[3];
    *(bf16x8*)&Ws[m * 256 + ((a ^ (m & 7)) * 8)] = v;
  }
#pragma unroll
  for (int i = 0; i < 4; ++i) {
    const int A = i * 512 + tid;            // 0..2047 -> W_h (atoms 16..31)
    const int m = A >> 4, a = 16 + (A & 15);
    f32x4 lo = *(const f32x4*)(W_h + A * 8);
    f32x4 hi = *(const f32x4*)(W_h + A * 8 + 4);
    bf16x8 v;
    v[0]=(__bf16)lo[0]; v[1]=(__bf16)lo[1]; v[2]=(__bf16)lo[2]; v[3]=(__bf16)lo[3];
    v[4]=(__bf16)hi[0]; v[5]=(__bf16)hi[1]; v[6]=(__bf16)hi[2]; v[7]=(__bf16)hi[3];
    *(bf16x8*)&Ws[m * 256 + ((a ^ (m & 7)) * 8)] = v;
  }
  __syncthreads();   // the ONLY barrier

  // ---- Convert X to resident B-fragments
  bf16x8 bfrag[8];
#pragma unroll
  for (int s = 0; s < 8; ++s) {
#pragma unroll
    for (int j = 0; j < 8; ++j) bfrag[s][j] = (__bf16)xs[s][j];
  }

  // ---- m-tile loop: A-fragments from LDS, 8 MFMA, store 16x16 tile
  float* outp = out + (size_t)b * 128 * NDIM + ncol;
#pragma unroll
  for (int mt = 0; mt < 8; ++mt) {
    f32x4 acc = {0.f, 0.f, 0.f, 0.f};
    const int m  = mt * 16 + l15;           // A row this lane supplies
    const int sw = m & 7;
#pragma unroll
    for (int s = 0; s < 8; ++s) {
      bf16x8 af = *(const bf16x8*)&Ws[m * 256 + (((s * 4 + quad) ^ sw) * 8)];
      acc = __builtin_amdgcn_mfma_f32_16x16x32_bf16(af, bfrag[s], acc, 0, 0, 0);
    }
    // D: col=l15, row=quad*4+r ; bias rows are 4 consecutive floats
    f32x4 be = *(const f32x4*)(b_e + mt * 16 + quad * 4);
    f32x4 bh = *(const f32x4*)(b_h + mt * 16 + quad * 4);
#pragma unroll
    for (int r = 0; r < 4; ++r) {
      __builtin_nontemporal_store(acc[r] + be[r] + bh[r],
          outp + (size_t)(mt * 16 + quad * 4 + r) * NDIM);
    }
  }
}

extern "C" void kernel_launch(void* const* d_in, const int* in_sizes, int n_in,
                              void* d_out, int out_size, void* d_ws, size_t ws_size,
                              hipStream_t stream) {
  // setup_inputs order: h_v(unused), h_w, e_vw, W_e, b_e, W_h, b_h
  const float* h_w  = (const float*)d_in[1];
  const float* e_vw = (const float*)d_in[2];
  const float* W_e  = (const float*)d_in[3];
  const float* b_e  = (const float*)d_in[4];
  const float* W_h  = (const float*)d_in[5];
  const float* b_h  = (const float*)d_in[6];
  float* out = (float*)d_out;

  msg_kernel<<<dim3(1024 * 4), dim3(512), 0, stream>>>(
      h_w, e_vw, W_e, b_e, W_h, b_h, out);
}